// Round 5
// baseline (396.576 us; speedup 1.0000x reference)
//
#include <hip/hip_runtime.h>
#include <hip/hip_bf16.h>
#include <stdint.h>

// DBlock: N=16, Cin=256, Cout=512, H=W=64
// NHWC bf16 implicit GEMM, mfma_f32_16x16x32_bf16.
// xb padded to [16][64][66][256] (zero cols wp=0,65) -> no w-halo masking.
// conv1: row-halo handled by staging from a zero buffer (no read-time masks).

typedef __bf16 bf8v __attribute__((ext_vector_type(8)));
typedef float  f4   __attribute__((ext_vector_type(4)));

#define G3F (1.0f / 48.0f)
#define G1F (1.0f / 16.0f)
#define SQRT2F 1.4142135623730951f

__device__ __forceinline__ float actf(float v) {
    return (v > 0.0f ? v : 0.2f * v) * SQRT2F;
}
__device__ __forceinline__ unsigned short f2bu(float f) {
    __hip_bfloat16 h = __float2bfloat16(f);
    return *reinterpret_cast<unsigned short*>(&h);
}
__device__ __forceinline__ bf8v ld8(const __hip_bfloat16* p) {
    return *reinterpret_cast<const bf8v*>(p);
}
__device__ __forceinline__ void llds16(const __hip_bfloat16* g, void* l) {
    __builtin_amdgcn_global_load_lds(
        (const __attribute__((address_space(1))) unsigned int*)g,
        (__attribute__((address_space(3))) unsigned int*)l, 16, 0, 0);
}

// ---------------------------------------------------------------------------
// p_pad: zero the two pad columns (wp=0, wp=65) of padded xb + the zero buffer
// ---------------------------------------------------------------------------
__global__ __launch_bounds__(256) void p_pad(__hip_bfloat16* __restrict__ xb,
                                             __hip_bfloat16* __restrict__ zbuf) {
    int idx = blockIdx.x * 256 + threadIdx.x;       // 65536
    int c8 = idx & 31, side = (idx >> 5) & 1, h = (idx >> 6) & 63, n = idx >> 12;
    int wp = side * 65;
    uint4 z = {0, 0, 0, 0};
    *reinterpret_cast<uint4*>(xb + (((size_t)(n * 64 + h) * 66 + wp) << 8) + c8 * 8) = z;
    if (blockIdx.x == 0 && threadIdx.x < 64)
        *reinterpret_cast<uint4*>(zbuf + (threadIdx.x << 3)) = z;
}

// ---------------------------------------------------------------------------
// p_xb: lat NCHW fp32 -> xb NHWC bf16 padded [16][64][66][256] (writes wp=1..64)
// ---------------------------------------------------------------------------
__global__ __launch_bounds__(256) void p_xb(const float* __restrict__ lat,
                                            __hip_bfloat16* __restrict__ xb) {
    __shared__ float tile[32][65];
    int bx = blockIdx.x;
    int cic = bx & 7, h = (bx >> 3) & 63, n = bx >> 9;
    int ci0 = cic * 32;
    int t = threadIdx.x;
    {
        int cir = t >> 3, wq = (t & 7) * 8;
        const float* src = lat + (((size_t)(n * 256 + ci0 + cir) * 64 + h) * 64 + wq);
        float4 v0 = *(const float4*)src;
        float4 v1 = *(const float4*)(src + 4);
        tile[cir][wq + 0] = v0.x; tile[cir][wq + 1] = v0.y;
        tile[cir][wq + 2] = v0.z; tile[cir][wq + 3] = v0.w;
        tile[cir][wq + 4] = v1.x; tile[cir][wq + 5] = v1.y;
        tile[cir][wq + 6] = v1.z; tile[cir][wq + 7] = v1.w;
    }
    __syncthreads();
    {
        int w = t >> 2, c8 = (t & 3) * 8;
        union { uint4 q; unsigned short h8[8]; } pk;
        #pragma unroll
        for (int j = 0; j < 8; ++j) pk.h8[j] = f2bu(tile[c8 + j][w]);
        __hip_bfloat16* dst = xb + (((size_t)(n * 64 + h) * 66 + (w + 1)) << 8) + ci0 + c8;
        *reinterpret_cast<uint4*>(dst) = pk.q;
    }
}

// ---------------------------------------------------------------------------
// Weight preps: fragment-linear bf16 (1 contiguous KB per wave A-load)
// ---------------------------------------------------------------------------
__global__ __launch_bounds__(256) void p_wA(const float* __restrict__ w,
                                            __hip_bfloat16* __restrict__ wA) {
    int idx = blockIdx.x * 256 + threadIdx.x;       // 73728
    int lane = idx & 63;
    int co16 = (idx >> 6) & 15;
    int q    = (idx >> 10) & 7;
    int t    = idx >> 13;
    int co = co16 * 16 + (lane & 15);
    int ci = q * 32 + (lane >> 4) * 8;
    union { uint4 v; unsigned short h8[8]; } pk;
    #pragma unroll
    for (int e = 0; e < 8; ++e)
        pk.h8[e] = f2bu(w[(size_t)(co * 256 + ci + e) * 9 + t] * G3F);
    *reinterpret_cast<uint4*>(wA + (size_t)idx * 8) = pk.v;
}
__global__ __launch_bounds__(256) void p_wD(const float* __restrict__ w,
                                            __hip_bfloat16* __restrict__ wD) {
    int idx = blockIdx.x * 256 + threadIdx.x;       // 147456
    int lane = idx & 63;
    int co16 = (idx >> 6) & 31;
    int q    = (idx >> 11) & 7;
    int t    = idx >> 14;
    int co = co16 * 16 + (lane & 15);
    int ci = q * 32 + (lane >> 4) * 8;
    union { uint4 v; unsigned short h8[8]; } pk;
    #pragma unroll
    for (int e = 0; e < 8; ++e)
        pk.h8[e] = f2bu(w[(size_t)(co * 256 + ci + e) * 9 + t] * G3F);
    *reinterpret_cast<uint4*>(wD + (size_t)idx * 8) = pk.v;
}
__global__ __launch_bounds__(256) void p_ws(const float* __restrict__ w,
                                            __hip_bfloat16* __restrict__ wst) {
    int idx = blockIdx.x * 256 + threadIdx.x;       // 131072
    wst[idx] = __float2bfloat16(w[idx] * G1F);
}

// ---------------------------------------------------------------------------
// fir2n: s2 = FIR4x4(xb, pad=1, down=2)  NHWC bf16 [16][32][32][256]
// ---------------------------------------------------------------------------
__global__ __launch_bounds__(256) void k_fir2n(const __hip_bfloat16* __restrict__ xb,
                                               __hip_bfloat16* __restrict__ s2) {
    int idx = blockIdx.x * 256 + threadIdx.x;       // 524288
    int c8 = idx & 31, ow = (idx >> 5) & 31, oh = (idx >> 10) & 31, n = idx >> 15;
    const float fk[4] = {0.125f, 0.375f, 0.375f, 0.125f};
    float a8[8];
    #pragma unroll
    for (int e = 0; e < 8; ++e) a8[e] = 0.0f;
    const __hip_bfloat16* src = xb + ((size_t)n * 64 * 66) * 256 + c8 * 8;
    #pragma unroll
    for (int i = 0; i < 4; ++i) {
        int rr = 2 * oh + i - 1;
        if ((unsigned)rr >= 64u) continue;
        #pragma unroll
        for (int j = 0; j < 4; ++j) {
            int wp = 2 * ow + j;                    // padded coord, always valid
            bf8v v = ld8(src + ((size_t)(rr * 66 + wp) << 8));
            float fw = fk[i] * fk[j];
            #pragma unroll
            for (int e = 0; e < 8; ++e) a8[e] += fw * (float)v[e];
        }
    }
    union { uint4 q; unsigned short h8[8]; } pk;
    #pragma unroll
    for (int e = 0; e < 8; ++e) pk.h8[e] = f2bu(a8[e]);
    *reinterpret_cast<uint4*>(s2 + (((size_t)(n * 1024 + oh * 32 + ow)) << 8) + c8 * 8) = pk.q;
}

// ---------------------------------------------------------------------------
// skipg: out = act(conv1x1(s2, wst)). Pure GEMM M=512 N=16384 K=256. WRITES out.
// ---------------------------------------------------------------------------
__global__ __launch_bounds__(256) void k_skipg(const __hip_bfloat16* __restrict__ s2,
                                               const __hip_bfloat16* __restrict__ wst,
                                               float* __restrict__ out) {
    const int lane = threadIdx.x & 63;
    const int wid  = threadIdx.x >> 6;
    const int wr = wid & 1, wc = wid >> 1;
    const int l15 = lane & 15, g = lane >> 4;

    int raw = blockIdx.x;
    int lg  = (raw & 7) * 64 + (raw >> 3);
    int cot = lg >> 7, pxt = lg & 127;
    int n = pxt >> 3, oh0 = (pxt & 7) * 4;

    f4 acc[4][4];
    #pragma unroll
    for (int m = 0; m < 4; ++m)
        #pragma unroll
        for (int nf = 0; nf < 4; ++nf)
            #pragma unroll
            for (int e = 0; e < 4; ++e) acc[m][nf][e] = 0.0f;

    #pragma unroll
    for (int k = 0; k < 8; ++k) {
        bf8v a_[4], b_[4];
        #pragma unroll
        for (int nf = 0; nf < 4; ++nf) {
            int oh = oh0 + wc * 2 + (nf >> 1);
            int ow = (nf & 1) * 16 + l15;
            b_[nf] = ld8(s2 + (((size_t)(n * 1024 + oh * 32 + ow)) << 8) + k * 32 + g * 8);
        }
        #pragma unroll
        for (int m = 0; m < 4; ++m) {
            int co = cot * 128 + wr * 64 + m * 16 + l15;
            a_[m] = ld8(wst + (size_t)co * 256 + k * 32 + g * 8);
        }
        #pragma unroll
        for (int m = 0; m < 4; ++m)
            #pragma unroll
            for (int nf = 0; nf < 4; ++nf)
                acc[m][nf] = __builtin_amdgcn_mfma_f32_16x16x32_bf16(
                    a_[m], b_[nf], acc[m][nf], 0, 0, 0);
    }
    #pragma unroll
    for (int m = 0; m < 4; ++m)
        #pragma unroll
        for (int nf = 0; nf < 4; ++nf) {
            f4 v = acc[m][nf];
            int oh = oh0 + wc * 2 + (nf >> 1);
            int ow = (nf & 1) * 16 + l15;
            int co = cot * 128 + wr * 64 + m * 16 + 4 * g;
            #pragma unroll
            for (int r = 0; r < 4; ++r)
                out[((size_t)(n * 512 + co + r)) * 1024 + oh * 32 + ow] = actf(v[r]);
        }
}

// ---------------------------------------------------------------------------
// conv1s: x1 = act(conv3x3(xb)) NHWC. Block 128co x 128px, 4 waves, 4 ci-chunks,
// LDS 33 KB -> 4 blocks/CU. Row halo staged from zero buffer: NO read masks.
// ---------------------------------------------------------------------------
__global__ __launch_bounds__(256, 4) void k_conv1s(const __hip_bfloat16* __restrict__ xb,
                                                   const __hip_bfloat16* __restrict__ wA,
                                                   const __hip_bfloat16* __restrict__ zbuf,
                                                   __hip_bfloat16* __restrict__ x1) {
    __shared__ uint4 smq[2112];                      // 33792 B
    char* smc = (char*)smq;
    const int tid  = threadIdx.x;
    const int lane = tid & 63;
    const int wid  = tid >> 6;
    const int wr = wid & 1, wc = wid >> 1;
    const int l15 = lane & 15, g = lane >> 4;

    int raw = blockIdx.x;
    int lg  = (raw & 7) * 128 + (raw >> 3);
    int cot = lg >> 9, pxt = lg & 511;
    int n = pxt >> 5, h0 = (pxt & 31) * 2;
    const size_t nb66 = (size_t)n * 64 * 66 * 256;
    const size_t nb   = (size_t)n * 4096 * 256;
    const char* wAc = (const char*)wA;

    f4 acc[4][4];
    #pragma unroll
    for (int m = 0; m < 4; ++m)
        #pragma unroll
        for (int nf = 0; nf < 4; ++nf)
            #pragma unroll
            for (int e = 0; e < 4; ++e) acc[m][nf][e] = 0.0f;

    #pragma unroll 1
    for (int ch = 0; ch < 4; ++ch) {
        if (ch) __syncthreads();
        // stage 4 rows x 66 wp x 64 ci = 33792 B; invalid rows read the zero buf
        for (int li = wid; li < 33; li += 4) {
            int gi = li * 64 + lane;                 // 0..2111
            int row = (gi >= 1584) ? 3 : (gi >= 1056) ? 2 : (gi >= 528) ? 1 : 0;
            int rem = gi - row * 528;
            int wp = rem >> 3;
            int c8 = (rem & 7) ^ (wp & 7);
            int rc = h0 - 1 + row;
            const __hip_bfloat16* src = ((unsigned)rc < 64u)
                ? xb + nb66 + (((size_t)(rc * 66 + wp)) << 8) + ch * 64 + c8 * 8
                : zbuf + (lane << 3);
            llds16(src, smc + li * 1024);
        }
        __syncthreads();

        #pragma unroll
        for (int kh = 0; kh < 3; ++kh) {
            #pragma unroll
            for (int kw = 0; kw < 3; ++kw) {
                #pragma unroll
                for (int qq = 0; qq < 2; ++qq) {
                    int c8r = qq * 4 + g;
                    bf8v b_[4];
                    #pragma unroll
                    for (int nf = 0; nf < 4; ++nf) {
                        int wp = nf * 16 + l15 + kw;           // 0..65
                        int off = (wc + kh) * 8448 + (wp * 8 + (c8r ^ (wp & 7))) * 16;
                        b_[nf] = *(const bf8v*)(smc + off);
                    }
                    int q = ch * 2 + qq;
                    #pragma unroll
                    for (int m = 0; m < 4; ++m) {
                        bf8v a = *(const bf8v*)(wAc +
                            ((size_t)(((kh * 3 + kw) * 8 + q) * 16 + cot * 8 + wr * 4 + m) << 10) +
                            (lane << 4));
                        #pragma unroll
                        for (int nf = 0; nf < 4; ++nf)
                            acc[m][nf] = __builtin_amdgcn_mfma_f32_16x16x32_bf16(
                                a, b_[nf], acc[m][nf], 0, 0, 0);
                    }
                }
            }
        }
    }

    // epilogue: act -> bf16, transpose via swizzled LDS, full-line stores
    __syncthreads();
    #pragma unroll
    for (int m = 0; m < 4; ++m)
        #pragma unroll
        for (int nf = 0; nf < 4; ++nf) {
            int p = wc * 64 + nf * 16 + l15;         // block-local px 0..127
            int co4 = wr * 16 + m * 4 + g;           // co granule 0..31
            int co4s = co4 ^ ((p & 15) << 1);
            union { unsigned long long u; unsigned short h4[4]; } pk;
            #pragma unroll
            for (int r = 0; r < 4; ++r) pk.h4[r] = f2bu(actf(acc[m][nf][r]));
            *reinterpret_cast<unsigned long long*>(smc + p * 256 + co4s * 8) = pk.u;
        }
    __syncthreads();
    {
        int p = tid >> 1, coh = tid & 1;
        int hh = h0 + (p >> 6), w = p & 63;
        __hip_bfloat16* dst = x1 + nb + (((size_t)(hh * 64 + w)) << 8) + cot * 128 + coh * 64;
        #pragma unroll
        for (int j = 0; j < 8; ++j) {
            int r2 = coh * 8 + j;                    // co octet 0..15
            int co4s = (2 * r2) ^ ((p & 15) << 1);
            uint4 v = *reinterpret_cast<const uint4*>(smc + p * 256 + co4s * 8);
            *reinterpret_cast<uint4*>(dst + j * 8) = v;
        }
    }
}

// ---------------------------------------------------------------------------
// fir1: xf = FIR4x4(x1, pad=2) NHWC bf16 [16][65][65][256]
// Separable, 4 outputs along ow per thread: 28 loads / 4 outputs.
// ---------------------------------------------------------------------------
__global__ __launch_bounds__(256) void k_fir1(const __hip_bfloat16* __restrict__ x1,
                                              __hip_bfloat16* __restrict__ xf) {
    int idx = blockIdx.x * 256 + threadIdx.x;  // 16*65*17*32 = 565,760 exact
    int c8 = idx & 31; int rest = idx >> 5;
    int owq = rest % 17; rest /= 17;
    int oh = rest % 65; int n = rest / 65;
    int ow0 = owq * 4; if (ow0 > 61) ow0 = 61;   // tail overlap (identical values)
    int ci = c8 * 8;
    const float fk[4] = {0.125f, 0.375f, 0.375f, 0.125f};
    const __hip_bfloat16* src = x1 + (size_t)n * 4096 * 256 + ci;

    float t[7][8];
    #pragma unroll
    for (int c = 0; c < 7; ++c) {
        #pragma unroll
        for (int e = 0; e < 8; ++e) t[c][e] = 0.0f;
        int col = ow0 - 2 + c;
        if ((unsigned)col >= 64u) continue;
        #pragma unroll
        for (int i = 0; i < 4; ++i) {
            int r = oh + i - 2;
            if ((unsigned)r >= 64u) continue;
            bf8v v = ld8(src + ((size_t)(r * 64 + col) << 8));
            float fw = fk[i];
            #pragma unroll
            for (int e = 0; e < 8; ++e) t[c][e] += fw * (float)v[e];
        }
    }
    #pragma unroll
    for (int o = 0; o < 4; ++o) {
        union { uint4 q; unsigned short h8[8]; } pk;
        #pragma unroll
        for (int e = 0; e < 8; ++e) {
            float s = fk[0] * t[o][e] + fk[1] * t[o + 1][e] +
                      fk[2] * t[o + 2][e] + fk[3] * t[o + 3][e];
            pk.h8[e] = f2bu(s);
        }
        *reinterpret_cast<uint4*>(
            xf + ((size_t)n * 4225 + oh * 65 + ow0 + o) * 256 + ci) = pk.q;
    }
}

// ---------------------------------------------------------------------------
// downs: out += act(conv3x3_s2(xf)). Block 128co x 128px (4 orows x 32),
// 4 waves (wave 32co x 128px), 8 ci-chunks of 32, LDS 38 KB -> 4 blocks/CU.
// Grid 512 = 4 cot x 16 n x 8 oht, XCD-swizzled. No halo.
// ---------------------------------------------------------------------------
__global__ __launch_bounds__(256, 4) void k_downs(const __hip_bfloat16* __restrict__ xf,
                                                  const __hip_bfloat16* __restrict__ wD,
                                                  float* __restrict__ out) {
    __shared__ uint4 smq[2432];                      // 38912 B
    char* smc = (char*)smq;
    const int tid  = threadIdx.x;
    const int lane = tid & 63;
    const int wid  = tid >> 6;
    const int l15  = lane & 15, g = lane >> 4;

    int raw = blockIdx.x;
    int lg  = (raw & 7) * 64 + (raw >> 3);           // 512 blocks, XCD-swizzled
    int cot = lg >> 7;                               // 0..3
    int rest = lg & 127;
    int n = rest >> 3, oht = rest & 7;
    int r0 = oht * 8;                                // input row base (rows r0..r0+8)
    const size_t nxf = (size_t)n * 4225 * 256;
    const char* wDc = (const char*)wD;

    f4 acc[2][8];
    #pragma unroll
    for (int m = 0; m < 2; ++m)
        #pragma unroll
        for (int nf = 0; nf < 8; ++nf)
            #pragma unroll
            for (int e = 0; e < 4; ++e) acc[m][nf][e] = 0.0f;

    #pragma unroll 1
    for (int ch = 0; ch < 8; ++ch) {
        if (ch) __syncthreads();
        // stage 9 rows x 65 wp x 32 ci = 2376 granules (row stride 264 granules)
        for (int li = wid; li < 38; li += 4) {
            int gi = li * 64 + lane;
            if (gi > 2375) gi = 2375;                // dup tail, lands past reads
            int row = gi / 264;
            int rem = gi - row * 264;
            int wpair = rem >> 3;
            int t4 = (rem & 7) ^ (wpair & 7);
            int odd = t4 >> 2, c8 = t4 & 3;
            int wp = wpair * 2 + odd; if (wp > 64) wp = 64;
            const __hip_bfloat16* src = xf + nxf +
                (((size_t)((r0 + row) * 65 + wp)) << 8) + ch * 32 + c8 * 8;
            llds16(src, smc + li * 1024);
        }
        __syncthreads();

        #pragma unroll
        for (int kh = 0; kh < 3; ++kh) {
            #pragma unroll
            for (int kw = 0; kw < 3; ++kw) {
                bf8v b_[8];
                #pragma unroll
                for (int nf = 0; nf < 8; ++nf) {
                    int ow = (nf & 1) * 16 + l15;
                    int wp = 2 * ow + kw;
                    int wpair = wp >> 1, odd = wp & 1;
                    int s8 = (g + 4 * odd) ^ (wpair & 7);
                    int off = ((2 * (nf >> 1) + kh) * 264 + wpair * 8 + s8) * 16;
                    b_[nf] = *(const bf8v*)(smc + off);
                }
                #pragma unroll
                for (int m = 0; m < 2; ++m) {
                    bf8v a = *(const bf8v*)(wDc +
                        ((size_t)(((kh * 3 + kw) * 8 + ch) * 32 + cot * 8 + wid * 2 + m) << 10) +
                        (lane << 4));
                    #pragma unroll
                    for (int nf = 0; nf < 8; ++nf)
                        acc[m][nf] = __builtin_amdgcn_mfma_f32_16x16x32_bf16(
                            a, b_[nf], acc[m][nf], 0, 0, 0);
                }
            }
        }
    }

    #pragma unroll
    for (int m = 0; m < 2; ++m)
        #pragma unroll
        for (int nf = 0; nf < 8; ++nf) {
            f4 v = acc[m][nf];
            int oh = oht * 4 + (nf >> 1);
            int ow = (nf & 1) * 16 + l15;
            int co = cot * 128 + wid * 32 + m * 16 + 4 * g;
            #pragma unroll
            for (int r = 0; r < 4; ++r) {
                size_t oi = ((size_t)(n * 512 + co + r)) * 1024 + oh * 32 + ow;
                out[oi] += actf(v[r]);
            }
        }
}

// ---------------------------------------------------------------------------
extern "C" void kernel_launch(void* const* d_in, const int* in_sizes, int n_in,
                              void* d_out, int out_size, void* d_ws, size_t ws_size,
                              hipStream_t stream) {
    const float* lat   = (const float*)d_in[0];
    const float* wconv = (const float*)d_in[1];
    const float* wdown = (const float*)d_in[2];
    const float* wskip = (const float*)d_in[3];
    float* out = (float*)d_out;

    // ws layout (total 71,967,744 B; round-1 proved >= 76.5 MB available):
    //   region0 [0, 34,611,200): xb padded (34,603,008) then xf (34,611,200)
    //   x1 at 34,611,200 (33,554,432); s2 overlays x1 base (dead before conv1s)
    //   wA 68,165,632 / wD 69,345,280 / wst 71,704,576 / zbuf 71,966,720 (1KB)
    char* base = (char*)d_ws;
    __hip_bfloat16* xb   = (__hip_bfloat16*)base;
    __hip_bfloat16* xf   = (__hip_bfloat16*)base;
    __hip_bfloat16* x1   = (__hip_bfloat16*)(base + 34611200);
    __hip_bfloat16* s2   = (__hip_bfloat16*)(base + 34611200);
    __hip_bfloat16* wA   = (__hip_bfloat16*)(base + 68165632);
    __hip_bfloat16* wD   = (__hip_bfloat16*)(base + 69345280);
    __hip_bfloat16* wst  = (__hip_bfloat16*)(base + 71704576);
    __hip_bfloat16* zbuf = (__hip_bfloat16*)(base + 71966720);

    hipLaunchKernelGGL(p_pad,   dim3(256),  dim3(256), 0, stream, xb, zbuf);
    hipLaunchKernelGGL(p_xb,    dim3(8192), dim3(256), 0, stream, lat,   xb);
    hipLaunchKernelGGL(p_wA,    dim3(288),  dim3(256), 0, stream, wconv, wA);
    hipLaunchKernelGGL(p_wD,    dim3(576),  dim3(256), 0, stream, wdown, wD);
    hipLaunchKernelGGL(p_ws,    dim3(512),  dim3(256), 0, stream, wskip, wst);
    hipLaunchKernelGGL(k_fir2n, dim3(2048), dim3(256), 0, stream, xb, s2);
    hipLaunchKernelGGL(k_skipg, dim3(512),  dim3(256), 0, stream, s2, wst, out);
    hipLaunchKernelGGL(k_conv1s, dim3(1024), dim3(256), 0, stream, xb, wA, zbuf, x1);
    hipLaunchKernelGGL(k_fir1,  dim3(2210), dim3(256), 0, stream, x1, xf);
    hipLaunchKernelGGL(k_downs, dim3(512),  dim3(256), 0, stream, xf, wD, out);
}

// Round 6
// 232.098 us; speedup vs baseline: 1.7087x; 1.7087x over previous
//
#include <hip/hip_runtime.h>
#include <hip/hip_bf16.h>
#include <stdint.h>

// DBlock: N=16, Cin=256, Cout=512, H=W=64
// NHWC bf16 implicit GEMM, mfma_f32_16x16x32_bf16.
// xb padded to [16][64][66][256] (zero cols wp=0,65) -> no w-halo masking.
// conv1: row-halo handled by staging from a zero buffer (no read-time masks).

typedef __bf16 bf8v __attribute__((ext_vector_type(8)));
typedef float  f4   __attribute__((ext_vector_type(4)));

#define G3F (1.0f / 48.0f)
#define G1F (1.0f / 16.0f)
#define SQRT2F 1.4142135623730951f

__device__ __forceinline__ float actf(float v) {
    return (v > 0.0f ? v : 0.2f * v) * SQRT2F;
}
__device__ __forceinline__ unsigned short f2bu(float f) {
    __hip_bfloat16 h = __float2bfloat16(f);
    return *reinterpret_cast<unsigned short*>(&h);
}
__device__ __forceinline__ bf8v ld8(const __hip_bfloat16* p) {
    return *reinterpret_cast<const bf8v*>(p);
}
__device__ __forceinline__ void llds16(const __hip_bfloat16* g, void* l) {
    __builtin_amdgcn_global_load_lds(
        (const __attribute__((address_space(1))) unsigned int*)g,
        (__attribute__((address_space(3))) unsigned int*)l, 16, 0, 0);
}

// ---------------------------------------------------------------------------
// p_pad: zero the two pad columns (wp=0, wp=65) of padded xb + the zero buffer
// ---------------------------------------------------------------------------
__global__ __launch_bounds__(256) void p_pad(__hip_bfloat16* __restrict__ xb,
                                             __hip_bfloat16* __restrict__ zbuf) {
    int idx = blockIdx.x * 256 + threadIdx.x;       // 65536
    int c8 = idx & 31, side = (idx >> 5) & 1, h = (idx >> 6) & 63, n = idx >> 12;
    int wp = side * 65;
    uint4 z = {0, 0, 0, 0};
    *reinterpret_cast<uint4*>(xb + (((size_t)(n * 64 + h) * 66 + wp) << 8) + c8 * 8) = z;
    if (blockIdx.x == 0 && threadIdx.x < 64)
        *reinterpret_cast<uint4*>(zbuf + (threadIdx.x << 3)) = z;
}

// ---------------------------------------------------------------------------
// p_xb: lat NCHW fp32 -> xb NHWC bf16 padded [16][64][66][256] (writes wp=1..64)
// ---------------------------------------------------------------------------
__global__ __launch_bounds__(256) void p_xb(const float* __restrict__ lat,
                                            __hip_bfloat16* __restrict__ xb) {
    __shared__ float tile[32][65];
    int bx = blockIdx.x;
    int cic = bx & 7, h = (bx >> 3) & 63, n = bx >> 9;
    int ci0 = cic * 32;
    int t = threadIdx.x;
    {
        int cir = t >> 3, wq = (t & 7) * 8;
        const float* src = lat + (((size_t)(n * 256 + ci0 + cir) * 64 + h) * 64 + wq);
        float4 v0 = *(const float4*)src;
        float4 v1 = *(const float4*)(src + 4);
        tile[cir][wq + 0] = v0.x; tile[cir][wq + 1] = v0.y;
        tile[cir][wq + 2] = v0.z; tile[cir][wq + 3] = v0.w;
        tile[cir][wq + 4] = v1.x; tile[cir][wq + 5] = v1.y;
        tile[cir][wq + 6] = v1.z; tile[cir][wq + 7] = v1.w;
    }
    __syncthreads();
    {
        int w = t >> 2, c8 = (t & 3) * 8;
        union { uint4 q; unsigned short h8[8]; } pk;
        #pragma unroll
        for (int j = 0; j < 8; ++j) pk.h8[j] = f2bu(tile[c8 + j][w]);
        __hip_bfloat16* dst = xb + (((size_t)(n * 64 + h) * 66 + (w + 1)) << 8) + ci0 + c8;
        *reinterpret_cast<uint4*>(dst) = pk.q;
    }
}

// ---------------------------------------------------------------------------
// Weight preps: fragment-linear bf16 (1 contiguous KB per wave A-load)
// ---------------------------------------------------------------------------
__global__ __launch_bounds__(256) void p_wA(const float* __restrict__ w,
                                            __hip_bfloat16* __restrict__ wA) {
    int idx = blockIdx.x * 256 + threadIdx.x;       // 73728
    int lane = idx & 63;
    int co16 = (idx >> 6) & 15;
    int q    = (idx >> 10) & 7;
    int t    = idx >> 13;
    int co = co16 * 16 + (lane & 15);
    int ci = q * 32 + (lane >> 4) * 8;
    union { uint4 v; unsigned short h8[8]; } pk;
    #pragma unroll
    for (int e = 0; e < 8; ++e)
        pk.h8[e] = f2bu(w[(size_t)(co * 256 + ci + e) * 9 + t] * G3F);
    *reinterpret_cast<uint4*>(wA + (size_t)idx * 8) = pk.v;
}
__global__ __launch_bounds__(256) void p_wD(const float* __restrict__ w,
                                            __hip_bfloat16* __restrict__ wD) {
    int idx = blockIdx.x * 256 + threadIdx.x;       // 147456
    int lane = idx & 63;
    int co16 = (idx >> 6) & 31;
    int q    = (idx >> 11) & 7;
    int t    = idx >> 14;
    int co = co16 * 16 + (lane & 15);
    int ci = q * 32 + (lane >> 4) * 8;
    union { uint4 v; unsigned short h8[8]; } pk;
    #pragma unroll
    for (int e = 0; e < 8; ++e)
        pk.h8[e] = f2bu(w[(size_t)(co * 256 + ci + e) * 9 + t] * G3F);
    *reinterpret_cast<uint4*>(wD + (size_t)idx * 8) = pk.v;
}
__global__ __launch_bounds__(256) void p_ws(const float* __restrict__ w,
                                            __hip_bfloat16* __restrict__ wst) {
    int idx = blockIdx.x * 256 + threadIdx.x;       // 131072
    wst[idx] = __float2bfloat16(w[idx] * G1F);
}

// ---------------------------------------------------------------------------
// fir2n: s2 = FIR4x4(xb, pad=1, down=2)  NHWC bf16 [16][32][32][256]
// ---------------------------------------------------------------------------
__global__ __launch_bounds__(256) void k_fir2n(const __hip_bfloat16* __restrict__ xb,
                                               __hip_bfloat16* __restrict__ s2) {
    int idx = blockIdx.x * 256 + threadIdx.x;       // 524288
    int c8 = idx & 31, ow = (idx >> 5) & 31, oh = (idx >> 10) & 31, n = idx >> 15;
    const float fk[4] = {0.125f, 0.375f, 0.375f, 0.125f};
    float a8[8];
    #pragma unroll
    for (int e = 0; e < 8; ++e) a8[e] = 0.0f;
    const __hip_bfloat16* src = xb + ((size_t)n * 64 * 66) * 256 + c8 * 8;
    #pragma unroll
    for (int i = 0; i < 4; ++i) {
        int rr = 2 * oh + i - 1;
        if ((unsigned)rr >= 64u) continue;
        #pragma unroll
        for (int j = 0; j < 4; ++j) {
            int wp = 2 * ow + j;                    // padded coord, always valid
            bf8v v = ld8(src + ((size_t)(rr * 66 + wp) << 8));
            float fw = fk[i] * fk[j];
            #pragma unroll
            for (int e = 0; e < 8; ++e) a8[e] += fw * (float)v[e];
        }
    }
    union { uint4 q; unsigned short h8[8]; } pk;
    #pragma unroll
    for (int e = 0; e < 8; ++e) pk.h8[e] = f2bu(a8[e]);
    *reinterpret_cast<uint4*>(s2 + (((size_t)(n * 1024 + oh * 32 + ow)) << 8) + c8 * 8) = pk.q;
}

// ---------------------------------------------------------------------------
// skipg: out = act(conv1x1(s2, wst)). Pure GEMM M=512 N=16384 K=256. WRITES out.
// ---------------------------------------------------------------------------
__global__ __launch_bounds__(256) void k_skipg(const __hip_bfloat16* __restrict__ s2,
                                               const __hip_bfloat16* __restrict__ wst,
                                               float* __restrict__ out) {
    const int lane = threadIdx.x & 63;
    const int wid  = threadIdx.x >> 6;
    const int wr = wid & 1, wc = wid >> 1;
    const int l15 = lane & 15, g = lane >> 4;

    int raw = blockIdx.x;
    int lg  = (raw & 7) * 64 + (raw >> 3);
    int cot = lg >> 7, pxt = lg & 127;
    int n = pxt >> 3, oh0 = (pxt & 7) * 4;

    f4 acc[4][4];
    #pragma unroll
    for (int m = 0; m < 4; ++m)
        #pragma unroll
        for (int nf = 0; nf < 4; ++nf)
            #pragma unroll
            for (int e = 0; e < 4; ++e) acc[m][nf][e] = 0.0f;

    #pragma unroll
    for (int k = 0; k < 8; ++k) {
        bf8v a_[4], b_[4];
        #pragma unroll
        for (int nf = 0; nf < 4; ++nf) {
            int oh = oh0 + wc * 2 + (nf >> 1);
            int ow = (nf & 1) * 16 + l15;
            b_[nf] = ld8(s2 + (((size_t)(n * 1024 + oh * 32 + ow)) << 8) + k * 32 + g * 8);
        }
        #pragma unroll
        for (int m = 0; m < 4; ++m) {
            int co = cot * 128 + wr * 64 + m * 16 + l15;
            a_[m] = ld8(wst + (size_t)co * 256 + k * 32 + g * 8);
        }
        #pragma unroll
        for (int m = 0; m < 4; ++m)
            #pragma unroll
            for (int nf = 0; nf < 4; ++nf)
                acc[m][nf] = __builtin_amdgcn_mfma_f32_16x16x32_bf16(
                    a_[m], b_[nf], acc[m][nf], 0, 0, 0);
    }
    #pragma unroll
    for (int m = 0; m < 4; ++m)
        #pragma unroll
        for (int nf = 0; nf < 4; ++nf) {
            f4 v = acc[m][nf];
            int oh = oh0 + wc * 2 + (nf >> 1);
            int ow = (nf & 1) * 16 + l15;
            int co = cot * 128 + wr * 64 + m * 16 + 4 * g;
            #pragma unroll
            for (int r = 0; r < 4; ++r)
                out[((size_t)(n * 512 + co + r)) * 1024 + oh * 32 + ow] = actf(v[r]);
        }
}

// ---------------------------------------------------------------------------
// conv1s: x1 = act(conv3x3(xb)) NHWC. Block 128co x 128px, 4 waves, 4 ci-chunks,
// LDS 33 KB -> 4 blocks/CU. Row halo staged from zero buffer: NO read masks.
// ---------------------------------------------------------------------------
__global__ __launch_bounds__(256, 4) void k_conv1s(const __hip_bfloat16* __restrict__ xb,
                                                   const __hip_bfloat16* __restrict__ wA,
                                                   const __hip_bfloat16* __restrict__ zbuf,
                                                   __hip_bfloat16* __restrict__ x1) {
    __shared__ uint4 smq[2112];                      // 33792 B
    char* smc = (char*)smq;
    const int tid  = threadIdx.x;
    const int lane = tid & 63;
    const int wid  = tid >> 6;
    const int wr = wid & 1, wc = wid >> 1;
    const int l15 = lane & 15, g = lane >> 4;

    int raw = blockIdx.x;
    int lg  = (raw & 7) * 128 + (raw >> 3);
    int cot = lg >> 9, pxt = lg & 511;
    int n = pxt >> 5, h0 = (pxt & 31) * 2;
    const size_t nb66 = (size_t)n * 64 * 66 * 256;
    const size_t nb   = (size_t)n * 4096 * 256;
    const char* wAc = (const char*)wA;

    f4 acc[4][4];
    #pragma unroll
    for (int m = 0; m < 4; ++m)
        #pragma unroll
        for (int nf = 0; nf < 4; ++nf)
            #pragma unroll
            for (int e = 0; e < 4; ++e) acc[m][nf][e] = 0.0f;

    #pragma unroll 1
    for (int ch = 0; ch < 4; ++ch) {
        if (ch) __syncthreads();
        // stage 4 rows x 66 wp x 64 ci = 33792 B; invalid rows read the zero buf
        for (int li = wid; li < 33; li += 4) {
            int gi = li * 64 + lane;                 // 0..2111
            int row = (gi >= 1584) ? 3 : (gi >= 1056) ? 2 : (gi >= 528) ? 1 : 0;
            int rem = gi - row * 528;
            int wp = rem >> 3;
            int c8 = (rem & 7) ^ (wp & 7);
            int rc = h0 - 1 + row;
            const __hip_bfloat16* src = ((unsigned)rc < 64u)
                ? xb + nb66 + (((size_t)(rc * 66 + wp)) << 8) + ch * 64 + c8 * 8
                : zbuf + (lane << 3);
            llds16(src, smc + li * 1024);
        }
        __syncthreads();

        #pragma unroll
        for (int kh = 0; kh < 3; ++kh) {
            #pragma unroll
            for (int kw = 0; kw < 3; ++kw) {
                #pragma unroll
                for (int qq = 0; qq < 2; ++qq) {
                    int c8r = qq * 4 + g;
                    bf8v b_[4];
                    #pragma unroll
                    for (int nf = 0; nf < 4; ++nf) {
                        int wp = nf * 16 + l15 + kw;           // 0..65
                        int off = (wc + kh) * 8448 + (wp * 8 + (c8r ^ (wp & 7))) * 16;
                        b_[nf] = *(const bf8v*)(smc + off);
                    }
                    int q = ch * 2 + qq;
                    #pragma unroll
                    for (int m = 0; m < 4; ++m) {
                        bf8v a = *(const bf8v*)(wAc +
                            ((size_t)(((kh * 3 + kw) * 8 + q) * 16 + cot * 8 + wr * 4 + m) << 10) +
                            (lane << 4));
                        #pragma unroll
                        for (int nf = 0; nf < 4; ++nf)
                            acc[m][nf] = __builtin_amdgcn_mfma_f32_16x16x32_bf16(
                                a, b_[nf], acc[m][nf], 0, 0, 0);
                    }
                }
            }
        }
    }

    // epilogue: act -> bf16, transpose via swizzled LDS, full-line stores
    __syncthreads();
    #pragma unroll
    for (int m = 0; m < 4; ++m)
        #pragma unroll
        for (int nf = 0; nf < 4; ++nf) {
            int p = wc * 64 + nf * 16 + l15;         // block-local px 0..127
            int co4 = wr * 16 + m * 4 + g;           // co granule 0..31
            int co4s = co4 ^ ((p & 15) << 1);
            union { unsigned long long u; unsigned short h4[4]; } pk;
            #pragma unroll
            for (int r = 0; r < 4; ++r) pk.h4[r] = f2bu(actf(acc[m][nf][r]));
            *reinterpret_cast<unsigned long long*>(smc + p * 256 + co4s * 8) = pk.u;
        }
    __syncthreads();
    {
        int p = tid >> 1, coh = tid & 1;
        int hh = h0 + (p >> 6), w = p & 63;
        __hip_bfloat16* dst = x1 + nb + (((size_t)(hh * 64 + w)) << 8) + cot * 128 + coh * 64;
        #pragma unroll
        for (int j = 0; j < 8; ++j) {
            int r2 = coh * 8 + j;                    // co octet 0..15
            int co4s = (2 * r2) ^ ((p & 15) << 1);
            uint4 v = *reinterpret_cast<const uint4*>(smc + p * 256 + co4s * 8);
            *reinterpret_cast<uint4*>(dst + j * 8) = v;
        }
    }
}

// ---------------------------------------------------------------------------
// fir1: xf = FIR4x4(x1, pad=2) NHWC bf16 [16][65][65][256]
// Separable, 4 outputs along ow per thread: 28 loads / 4 outputs.
// ---------------------------------------------------------------------------
__global__ __launch_bounds__(256) void k_fir1(const __hip_bfloat16* __restrict__ x1,
                                              __hip_bfloat16* __restrict__ xf) {
    int idx = blockIdx.x * 256 + threadIdx.x;  // 16*65*17*32 = 565,760 exact
    int c8 = idx & 31; int rest = idx >> 5;
    int owq = rest % 17; rest /= 17;
    int oh = rest % 65; int n = rest / 65;
    int ow0 = owq * 4; if (ow0 > 61) ow0 = 61;   // tail overlap (identical values)
    int ci = c8 * 8;
    const float fk[4] = {0.125f, 0.375f, 0.375f, 0.125f};
    const __hip_bfloat16* src = x1 + (size_t)n * 4096 * 256 + ci;

    float t[7][8];
    #pragma unroll
    for (int c = 0; c < 7; ++c) {
        #pragma unroll
        for (int e = 0; e < 8; ++e) t[c][e] = 0.0f;
        int col = ow0 - 2 + c;
        if ((unsigned)col >= 64u) continue;
        #pragma unroll
        for (int i = 0; i < 4; ++i) {
            int r = oh + i - 2;
            if ((unsigned)r >= 64u) continue;
            bf8v v = ld8(src + ((size_t)(r * 64 + col) << 8));
            float fw = fk[i];
            #pragma unroll
            for (int e = 0; e < 8; ++e) t[c][e] += fw * (float)v[e];
        }
    }
    #pragma unroll
    for (int o = 0; o < 4; ++o) {
        union { uint4 q; unsigned short h8[8]; } pk;
        #pragma unroll
        for (int e = 0; e < 8; ++e) {
            float s = fk[0] * t[o][e] + fk[1] * t[o + 1][e] +
                      fk[2] * t[o + 2][e] + fk[3] * t[o + 3][e];
            pk.h8[e] = f2bu(s);
        }
        *reinterpret_cast<uint4*>(
            xf + ((size_t)n * 4225 + oh * 65 + ow0 + o) * 256 + ci) = pk.q;
    }
}

// ---------------------------------------------------------------------------
// downs: out += act(conv3x3_s2(xf)). Block 128co x 64px (2 orows x 32),
// 4 waves (wave 32co x 64px), 8 ci-chunks of 32, LDS 21.5 KB -> 4 blocks/CU.
// Grid 1024 = 4 cot x 16 n x 16 oht, XCD-swizzled. No halo.
// (round-4 proven shape; round-5's acc[2][8] variant spilled to scratch)
// ---------------------------------------------------------------------------
__global__ __launch_bounds__(256, 4) void k_downs(const __hip_bfloat16* __restrict__ xf,
                                                  const __hip_bfloat16* __restrict__ wD,
                                                  float* __restrict__ out) {
    __shared__ uint4 smq[1344];                      // 21504 B
    char* smc = (char*)smq;
    const int tid  = threadIdx.x;
    const int lane = tid & 63;
    const int wid  = tid >> 6;
    const int l15  = lane & 15, g = lane >> 4;

    int raw = blockIdx.x;
    int lg  = (raw & 7) * 128 + (raw >> 3);
    int cot = lg >> 8;                               // 0..3
    int rest = lg & 255;
    int n = rest >> 4, oht = rest & 15;
    int r0 = oht * 4;
    const size_t nxf = (size_t)n * 4225 * 256;
    const char* wDc = (const char*)wD;

    f4 acc[2][4];
    #pragma unroll
    for (int m = 0; m < 2; ++m)
        #pragma unroll
        for (int nf = 0; nf < 4; ++nf)
            #pragma unroll
            for (int e = 0; e < 4; ++e) acc[m][nf][e] = 0.0f;

    #pragma unroll 1
    for (int ch = 0; ch < 8; ++ch) {
        if (ch) __syncthreads();
        // stage 5 rows x 65 wp x 32 ci; granule = row*264 + wpair*8 + slot8
        for (int li = wid; li < 21; li += 4) {
            int gi = li * 64 + lane;
            if (gi > 1319) gi = 1319;
            int row = (gi >= 1056) ? 4 : (gi >= 792) ? 3 : (gi >= 528) ? 2 :
                      (gi >= 264) ? 1 : 0;
            int rem = gi - row * 264;
            int wpair = rem >> 3;
            int t4 = (rem & 7) ^ (wpair & 7);        // c8 + 4*odd
            int odd = t4 >> 2, c8 = t4 & 3;
            int wp = wpair * 2 + odd; if (wp > 64) wp = 64;
            const __hip_bfloat16* src = xf + nxf +
                (((size_t)((r0 + row) * 65 + wp)) << 8) + ch * 32 + c8 * 8;
            llds16(src, smc + li * 1024);
        }
        __syncthreads();

        #pragma unroll
        for (int kh = 0; kh < 3; ++kh) {
            #pragma unroll
            for (int kw = 0; kw < 3; ++kw) {
                bf8v b_[4];
                #pragma unroll
                for (int nf = 0; nf < 4; ++nf) {
                    int ow = (nf & 1) * 16 + l15;
                    int wp = 2 * ow + kw;
                    int wpair = wp >> 1, odd = wp & 1;
                    int s8 = (g + 4 * odd) ^ (wpair & 7);
                    int off = ((2 * (nf >> 1) + kh) * 264 + wpair * 8 + s8) * 16;
                    b_[nf] = *(const bf8v*)(smc + off);
                }
                #pragma unroll
                for (int m = 0; m < 2; ++m) {
                    bf8v a = *(const bf8v*)(wDc +
                        ((size_t)(((kh * 3 + kw) * 8 + ch) * 32 + cot * 8 + wid * 2 + m) << 10) +
                        (lane << 4));
                    #pragma unroll
                    for (int nf = 0; nf < 4; ++nf)
                        acc[m][nf] = __builtin_amdgcn_mfma_f32_16x16x32_bf16(
                            a, b_[nf], acc[m][nf], 0, 0, 0);
                }
            }
        }
    }

    #pragma unroll
    for (int m = 0; m < 2; ++m)
        #pragma unroll
        for (int nf = 0; nf < 4; ++nf) {
            f4 v = acc[m][nf];
            int oh = oht * 2 + (nf >> 1);
            int ow = (nf & 1) * 16 + l15;
            int co = cot * 128 + wid * 32 + m * 16 + 4 * g;
            #pragma unroll
            for (int r = 0; r < 4; ++r) {
                size_t oi = ((size_t)(n * 512 + co + r)) * 1024 + oh * 32 + ow;
                out[oi] += actf(v[r]);
            }
        }
}

// ---------------------------------------------------------------------------
extern "C" void kernel_launch(void* const* d_in, const int* in_sizes, int n_in,
                              void* d_out, int out_size, void* d_ws, size_t ws_size,
                              hipStream_t stream) {
    const float* lat   = (const float*)d_in[0];
    const float* wconv = (const float*)d_in[1];
    const float* wdown = (const float*)d_in[2];
    const float* wskip = (const float*)d_in[3];
    float* out = (float*)d_out;

    // ws layout (total 71,967,744 B):
    //   region0 [0, 34,611,200): xb padded (34,603,008) then xf (34,611,200)
    //   x1 at 34,611,200 (33,554,432); s2 overlays x1 base (dead before conv1s)
    //   wA 68,165,632 / wD 69,345,280 / wst 71,704,576 / zbuf 71,966,720 (1KB)
    char* base = (char*)d_ws;
    __hip_bfloat16* xb   = (__hip_bfloat16*)base;
    __hip_bfloat16* xf   = (__hip_bfloat16*)base;
    __hip_bfloat16* x1   = (__hip_bfloat16*)(base + 34611200);
    __hip_bfloat16* s2   = (__hip_bfloat16*)(base + 34611200);
    __hip_bfloat16* wA   = (__hip_bfloat16*)(base + 68165632);
    __hip_bfloat16* wD   = (__hip_bfloat16*)(base + 69345280);
    __hip_bfloat16* wst  = (__hip_bfloat16*)(base + 71704576);
    __hip_bfloat16* zbuf = (__hip_bfloat16*)(base + 71966720);

    hipLaunchKernelGGL(p_pad,   dim3(256),  dim3(256), 0, stream, xb, zbuf);
    hipLaunchKernelGGL(p_xb,    dim3(8192), dim3(256), 0, stream, lat,   xb);
    hipLaunchKernelGGL(p_wA,    dim3(288),  dim3(256), 0, stream, wconv, wA);
    hipLaunchKernelGGL(p_wD,    dim3(576),  dim3(256), 0, stream, wdown, wD);
    hipLaunchKernelGGL(p_ws,    dim3(512),  dim3(256), 0, stream, wskip, wst);
    hipLaunchKernelGGL(k_fir2n, dim3(2048), dim3(256), 0, stream, xb, s2);
    hipLaunchKernelGGL(k_skipg, dim3(512),  dim3(256), 0, stream, s2, wst, out);
    hipLaunchKernelGGL(k_conv1s, dim3(1024), dim3(256), 0, stream, xb, wA, zbuf, x1);
    hipLaunchKernelGGL(k_fir1,  dim3(2210), dim3(256), 0, stream, x1, xf);
    hipLaunchKernelGGL(k_downs, dim3(1024), dim3(256), 0, stream, xf, wD, out);
}